// Round 8
// baseline (247.631 us; speedup 1.0000x reference)
//
#include <hip/hip_runtime.h>
#include <hip/hip_bf16.h>
#include <math.h>

#define B_ 8
#define S_ 2048
#define D_ 1024
#define H_ 64
#define M_ (B_*S_)
#define SPLIT 4
#define KPS (S_/SPLIT)   // 512 keys per split

typedef __attribute__((ext_vector_type(8))) short bf16x8;
typedef __attribute__((ext_vector_type(8))) unsigned short u16x8;
typedef __attribute__((ext_vector_type(4))) float f32x4;

__device__ inline unsigned short f2bf(float f) {
    unsigned int u = __builtin_bit_cast(unsigned int, f);
    u += 0x7fffu + ((u >> 16) & 1u);   // round-to-nearest-even
    return (unsigned short)(u >> 16);
}

// async global->LDS, 16B per lane (global side carries any swizzle).
__device__ inline void async16(const void* g, void* l) {
    __builtin_amdgcn_global_load_lds((const __attribute__((address_space(1))) void*)g,
                                     (__attribute__((address_space(3))) void*)l, 16, 0, 0);
}

// mask -> multiplicative 1.0/0.0. Layout sniff: jax bool may be 1-byte or int32.
__global__ __launch_bounds__(256) void mask_kernel(const unsigned char* __restrict__ mask,
                                                   float* __restrict__ mmul, int n) {
    int j = blockIdx.x * 256 + threadIdx.x;
    if (j >= n) return;
    bool boolLayout = mask[1] != 0;
    int mv = boolLayout ? (int)mask[j] : ((const int*)mask)[j];
    mmul[j] = mv ? 1.0f : 0.0f;
}

// Transpose W[1024][64] fp32 -> Wt[64][1024] bf16, one matrix per blockIdx.y.
__global__ __launch_bounds__(256) void wprep_kernel(
    const float* __restrict__ Wq, const float* __restrict__ Wk, const float* __restrict__ Wv,
    unsigned short* __restrict__ Wt)
{
    const int m = blockIdx.y;
    const float* W = (m == 0) ? Wq : (m == 1) ? Wk : Wv;
    unsigned short* Wo = Wt + (size_t)m * 64 * 1024;
    __shared__ unsigned short T[64][65];
    const int t = threadIdx.x;
    const int k0 = blockIdx.x * 64;
    #pragma unroll
    for (int i = 0; i < 16; i++) {
        int vi = t + i * 256;
        int kk = vi >> 6, n = vi & 63;
        T[kk][n] = f2bf(W[(size_t)(k0 + kk) * 64 + n]);
    }
    __syncthreads();
    #pragma unroll
    for (int i = 0; i < 4; i++) {
        int vi = t + i * 256;
        int n = vi >> 4, k4 = vi & 15;
        ushort4 u;
        u.x = T[k4*4+0][n]; u.y = T[k4*4+1][n]; u.z = T[k4*4+2][n]; u.w = T[k4*4+3][n];
        *(ushort4*)&Wo[(size_t)n * 1024 + k0 + k4*4] = u;
    }
}

// x[M,1024] @ W[1024,64].
// Round-6 model (fits all 6 prior variants): the memory path serves wave
// loads by DISTINCT 128B LINES per instruction. Copy-like patterns (8
// lines/inst) reach 6.3 TB/s; per-lane row-strided patterns (16-64
// lines/inst) cap at ~3.6 TB/s -- and L3-resident replays are equally slow
// (per-CU line-service limit, not HBM). R0 was line-optimal but 55%-duty
// (drain+barrier x16); deep-pipeline variants were line-pessimal. This
// version combines BOTH:
//   * ALL staging via global_load_lds with 8-lines/inst patterns:
//     A inst = 4 rows x 256B contiguous; B inst = 8 rows x 128B contiguous.
//   * TRIPLE-buffered segments (K=64): A 3x16KB fp32 + B 3x8KB bf16 = 72KB,
//     2 blocks/CU. Stage s+2 issued in segment s -> the top-of-segment
//     vmcnt(6) waits for stage(s) issued TWO segments earlier (~2 segment
//     times of latency cover). One barrier per segment; stage(s+2) targets
//     the buffer freed by compute(s-1) strictly behind that barrier.
//   * XOR unit swizzles (16B units): A slot = u ^ (r&15), B slot = u ^ (n&7),
//     applied on the pre-swizzled GLOBAL source and identically on the LDS
//     read (both-sides involution) -> 2-way max bank aliasing (free).
// R7 FIX: COMPUTE's A-row read was `lrow*64` -- missing the wave offset.
// Each wave owns rows w*16+lrow; ((w*16+lrow)&15)==lrow so the XOR swizzle
// term is unchanged. One-index fix, everything else identical to R6.
__global__ __launch_bounds__(256) void proj_kernel(
    const float* __restrict__ q, const float* __restrict__ kx, const float* __restrict__ vx,
    const unsigned short* __restrict__ Wt,
    unsigned short* __restrict__ qp, unsigned short* __restrict__ kp, unsigned short* __restrict__ vpT)
{
    __shared__ float          As[3][64 * 64];   // [buf][r*64 + slot*4] 16KB each
    __shared__ unsigned short Bs[3][64 * 64];   // [buf][n*64 + slot*8]  8KB each

    const int m = blockIdx.y;
    const float* x = (m == 0) ? q : (m == 1) ? kx : vx;
    const unsigned short* Wm = Wt + (size_t)m * 64 * 1024;

    const int t = threadIdx.x;
    const int w = t >> 6, l = t & 63;
    const int lrow = l & 15, quad = l >> 4;
    const int row0 = blockIdx.x * 64;
    const int arow = w * 16 + lrow;             // this wave's A row

    f32x4 acc[4] = {};

#define STAGE(s, Ad, Bd) do { \
    _Pragma("unroll") \
    for (int j_ = 0; j_ < 4; j_++) {        /* A: 64r x 64k fp32, 4r/inst */ \
        int p_ = j_ * 256 + t; \
        int r_ = p_ >> 4, u_ = p_ & 15; \
        async16(x + (size_t)(row0 + r_) * D_ + (s) * 64 + ((u_ ^ (r_ & 15)) << 2), \
                (Ad) + p_ * 4); \
    } \
    _Pragma("unroll") \
    for (int j_ = 0; j_ < 2; j_++) {        /* B: 64n x 64k bf16, 8n/inst */ \
        int p_ = j_ * 256 + t; \
        int n_ = p_ >> 3, ku_ = p_ & 7; \
        async16(Wm + (size_t)n_ * 1024 + (s) * 64 + ((ku_ ^ (n_ & 7)) << 3), \
                (Bd) + p_ * 8); \
    } \
    asm volatile("" ::: "memory"); } while (0)

#define COMPUTE(Aa, Ba) do { \
    _Pragma("unroll") \
    for (int kk_ = 0; kk_ < 2; kk_++) { \
        const int su_ = kk_ * 8 + quad * 2; \
        f32x4 a0_ = *(const f32x4*)&(Aa)[arow * 64 + (((su_    ) ^ lrow) << 2)]; \
        f32x4 a1_ = *(const f32x4*)&(Aa)[arow * 64 + (((su_ + 1) ^ lrow) << 2)]; \
        bf16x8 af_; \
        af_[0] = (short)f2bf(a0_.x); af_[1] = (short)f2bf(a0_.y); \
        af_[2] = (short)f2bf(a0_.z); af_[3] = (short)f2bf(a0_.w); \
        af_[4] = (short)f2bf(a1_.x); af_[5] = (short)f2bf(a1_.y); \
        af_[6] = (short)f2bf(a1_.z); af_[7] = (short)f2bf(a1_.w); \
        _Pragma("unroll") \
        for (int c_ = 0; c_ < 4; c_++) { \
            const int n_ = c_ * 16 + lrow; \
            const int sb_ = (kk_ * 4 + quad) ^ (lrow & 7); \
            bf16x8 b_ = *(const bf16x8*)&(Ba)[n_ * 64 + sb_ * 8]; \
            acc[c_] = __builtin_amdgcn_mfma_f32_16x16x32_bf16(af_, b_, acc[c_], 0, 0, 0); \
        } \
    } } while (0)

    // rotating buffer pointers: Aa/Ba = compute, Ac/Bc = stage target
    float *Aa = &As[0][0], *Ab = &As[1][0], *Ac = &As[2][0];
    unsigned short *Ba = &Bs[0][0], *Bb2 = &Bs[1][0], *Bc = &Bs[2][0];

    STAGE(0, Aa, Ba);
    STAGE(1, Ab, Bb2);

    // segments 0..13: wait stage(s) (12 in flight -> vmcnt(6)), stage s+2
    #pragma unroll 1
    for (int s = 0; s < 14; ++s) {
        asm volatile("s_waitcnt vmcnt(6)\n\ts_barrier" ::: "memory");
        STAGE(s + 2, Ac, Bc);
        COMPUTE(Aa, Ba);
        float* ta = Aa; Aa = Ab; Ab = Ac; Ac = ta;
        unsigned short* tb = Ba; Ba = Bb2; Bb2 = Bc; Bc = tb;
    }
    // segment 14: stage(14) done when stage(15)'s 6 remain
    asm volatile("s_waitcnt vmcnt(6)\n\ts_barrier" ::: "memory");
    COMPUTE(Aa, Ba);
    // segment 15: drain
    asm volatile("s_waitcnt vmcnt(0)\n\ts_barrier" ::: "memory");
    COMPUTE(Ab, Bb2);

#undef STAGE
#undef COMPUTE

    const int orow = row0 + w * 16 + quad * 4;
    if (m < 2) {
        unsigned short* outp = (m == 0) ? qp : kp;
        const float sc = (m == 0) ? 0.125f : 1.0f;   // fold attn scale into qp
        #pragma unroll
        for (int c = 0; c < 4; c++)
            #pragma unroll
            for (int rr = 0; rr < 4; rr++)
                outp[(size_t)(orow + rr) * H_ + c * 16 + lrow] = f2bf(acc[c][rr] * sc);
    } else {
        // vpT[b][h][s], s0..s0+3 contiguous per lane -> 8B stores
        const int bb = orow >> 11;
        const int s0 = orow & (S_ - 1);
        #pragma unroll
        for (int c = 0; c < 4; c++) {
            ushort4 u;
            u.x = f2bf(acc[c][0]); u.y = f2bf(acc[c][1]);
            u.z = f2bf(acc[c][2]); u.w = f2bf(acc[c][3]);
            *(ushort4*)&vpT[((size_t)bb * H_ + c * 16 + lrow) * S_ + s0] = u;
        }
    }
}

// Flash attention partial: block = (q-tile 64, batch, key-split). Max-free
// single-pass exp => partials over disjoint key ranges combine by addition.
// K and V^T tiles async-staged (L2-resident -> cheap barrier drain).
__global__ __launch_bounds__(256) void attn_kernel(
    const unsigned short* __restrict__ qp, const unsigned short* __restrict__ kp,
    const unsigned short* __restrict__ vpT, const float* __restrict__ mmul,
    float* __restrict__ po, float* __restrict__ pl)
{
    __shared__ unsigned short Qs[64][72];
    __shared__ unsigned short Ps[64][72];
    __shared__ unsigned short Ks[64 * 64];   // swizzled chunks [key][h]
    __shared__ unsigned short Vt[64 * 64];   // swizzled chunks [h][key]

    const int t = threadIdx.x;
    const int w = t >> 6, l = t & 63;
    const int lrow = l & 15, quad = l >> 4;
    const int b = blockIdx.y, q0 = blockIdx.x * 64, split = blockIdx.z;
    const int key0 = split * KPS;
    const size_t basebs = (size_t)b * S_;
    const unsigned short* vb = vpT + (size_t)b * H_ * S_;

    #pragma unroll
    for (int i = 0; i < 2; i++) {            // Q tile once: 512 16B-chunks
        int p = t + i * 256;
        int r = p >> 3, c8 = p & 7;
        u16x8 u = *(const u16x8*)&qp[(basebs + q0 + r) * H_ + c8 * 8];
        *(u16x8*)&Qs[r][c8 * 8] = u;
    }

    float lsum[4] = {0.f, 0.f, 0.f, 0.f};
    f32x4 o[4] = {};

    for (int kt = 0; kt < KPS / 64; kt++) {
        const int k0 = key0 + kt * 64;
        __syncthreads();                     // prev tile's LDS reads done
        #pragma unroll
        for (int j = 0; j < 2; j++) {        // K tile: 512 chunks
            int p = (w * 2 + j) * 64 + l;
            int r = p >> 3;
            int c8 = (p & 7) ^ (r & 7);
            async16(&kp[(basebs + k0 + r) * H_ + c8 * 8], &Ks[p * 8]);
        }
        #pragma unroll
        for (int j = 0; j < 2; j++) {        // V^T tile: 512 chunks
            int p = (w * 2 + j) * 64 + l;
            int h = p >> 3;
            int c8 = (p & 7) ^ (h & 7);
            async16(&vb[(size_t)h * S_ + k0 + c8 * 8], &Vt[p * 8]);
        }
        float mm[4];
        #pragma unroll
        for (int c = 0; c < 4; c++) mm[c] = mmul[basebs + k0 + c*16 + lrow];
        __syncthreads();                     // drain async queue

        // S = Q K^T (pre-scaled by 1/8 via qp)
        f32x4 s[4] = {};
        #pragma unroll
        for (int kk = 0; kk < 2; kk++) {
            bf16x8 aq = *(const bf16x8*)&Qs[w*16 + lrow][kk*32 + quad*8];
            #pragma unroll
            for (int c = 0; c < 4; c++) {
                const int n = c*16 + lrow;
                bf16x8 bk = *(const bf16x8*)&Ks[(n * 8 + ((kk*4 + quad) ^ (n & 7))) * 8];
                s[c] = __builtin_amdgcn_mfma_f32_16x16x32_bf16(aq, bk, s[c], 0, 0, 0);
            }
        }
        // single-pass softmax numerator; sum deferred
        #pragma unroll
        for (int r = 0; r < 4; r++) {
            float p0 = __expf(s[0][r]) * mm[0];
            float p1 = __expf(s[1][r]) * mm[1];
            float p2 = __expf(s[2][r]) * mm[2];
            float p3 = __expf(s[3][r]) * mm[3];
            lsum[r] += (p0 + p1) + (p2 + p3);
            const int pr = w*16 + quad*4 + r;
            Ps[pr][ 0 + lrow] = f2bf(p0);
            Ps[pr][16 + lrow] = f2bf(p1);
            Ps[pr][32 + lrow] = f2bf(p2);
            Ps[pr][48 + lrow] = f2bf(p3);
        }
        // Ps rows [w*16, w*16+16) wave-local: no barrier needed
        #pragma unroll
        for (int kk = 0; kk < 2; kk++) {
            bf16x8 ap = *(const bf16x8*)&Ps[w*16 + lrow][kk*32 + quad*8];
            #pragma unroll
            for (int c = 0; c < 4; c++) {
                const int h = c*16 + lrow;
                bf16x8 bv = *(const bf16x8*)&Vt[(h * 8 + ((kk*4 + quad) ^ (h & 7))) * 8];
                o[c] = __builtin_amdgcn_mfma_f32_16x16x32_bf16(ap, bv, o[c], 0, 0, 0);
            }
        }
    }

    float* pob = po + (size_t)split * M_ * H_;
    float* plb = pl + (size_t)split * M_;
    #pragma unroll
    for (int r = 0; r < 4; r++) {
        #pragma unroll
        for (int d = 1; d < 16; d <<= 1)
            lsum[r] += __shfl_xor(lsum[r], d, 64);
        const size_t row = basebs + q0 + w*16 + quad*4 + r;
        if (lrow == 0) plb[row] = lsum[r];
        #pragma unroll
        for (int c = 0; c < 4; c++)
            pob[row * H_ + c*16 + lrow] = o[c][r];
    }
}

// out = (sum_s po[s]) / (sum_s pl[s]); one float4 per thread.
__global__ __launch_bounds__(256) void combine_kernel(
    const float* __restrict__ po, const float* __restrict__ pl, float* __restrict__ out)
{
    const int idx = blockIdx.x * 256 + threadIdx.x;
    const size_t row = idx >> 4;
    const int c4 = (idx & 15) * 4;
    float lt = 0.f;
    #pragma unroll
    for (int s = 0; s < SPLIT; s++) lt += pl[(size_t)s * M_ + row];
    f32x4 acc = {};
    #pragma unroll
    for (int s = 0; s < SPLIT; s++) {
        const f32x4 p = *(const f32x4*)&po[((size_t)s * M_ + row) * H_ + c4];
        acc += p;
    }
    const float inv = 1.0f / lt;
    f32x4 r = acc * inv;
    *(f32x4*)&out[row * H_ + c4] = r;
}

extern "C" void kernel_launch(void* const* d_in, const int* in_sizes, int n_in,
                              void* d_out, int out_size, void* d_ws, size_t ws_size,
                              hipStream_t stream) {
    const float* q  = (const float*)d_in[0];
    const float* k  = (const float*)d_in[1];
    const float* v  = (const float*)d_in[2];
    const unsigned char* mask = (const unsigned char*)d_in[3];
    const float* Wq = (const float*)d_in[4];
    const float* Wk = (const float*)d_in[5];
    const float* Wv = (const float*)d_in[6];
    float* out = (float*)d_out;

    unsigned short* qp  = (unsigned short*)d_ws;         // 2 MB
    unsigned short* kp  = qp + (size_t)M_ * H_;          // 2 MB
    unsigned short* vpT = kp + (size_t)M_ * H_;          // 2 MB, [b][h][s]
    float* mmul = (float*)(vpT + (size_t)M_ * H_);       // 64 KB
    unsigned short* Wt = (unsigned short*)(mmul + M_);   // 384 KB
    float* po = (float*)(Wt + (size_t)3 * 64 * 1024);    // 16.8 MB
    float* pl = po + (size_t)SPLIT * M_ * H_;            // 256 KB

    wprep_kernel<<<dim3(16, 3), dim3(256), 0, stream>>>(Wq, Wk, Wv, Wt);
    mask_kernel<<<dim3((M_ + 255)/256), dim3(256), 0, stream>>>(mask, mmul, M_);
    proj_kernel<<<dim3(M_/64, 3), dim3(256), 0, stream>>>(q, k, v, Wt, qp, kp, vpT);
    attn_kernel<<<dim3(S_/64, B_, SPLIT), dim3(256), 0, stream>>>(qp, kp, vpT, mmul, po, pl);
    combine_kernel<<<dim3(M_*16/256), dim3(256), 0, stream>>>(po, pl, out);
}